// Round 1
// 782.766 us; speedup vs baseline: 1.2704x; 1.2704x over previous
//
#include <hip/hip_runtime.h>

#define N_NODES 100000
#define N_EDGES 3200000
#define DIM 256

typedef _Float16 half_t;
typedef __attribute__((ext_vector_type(4))) _Float16 half4;
typedef __attribute__((ext_vector_type(8))) _Float16 half8;
typedef __attribute__((ext_vector_type(4))) float floatx4;

// ---------------------------------------------------------------------------
// W cast+transpose: wT[n][k] = (f16) w[k][n].  256x256, grid(8,8) x 256 thr.
// ---------------------------------------------------------------------------
__global__ __launch_bounds__(256) void castw_kernel(const float* __restrict__ w,
                                                    half_t* __restrict__ wT) {
    __shared__ float tile[32][33];
    int bk = blockIdx.x * 32;  // k block
    int bn = blockIdx.y * 32;  // n block
    int tx = threadIdx.x & 31, ty = threadIdx.x >> 5;  // 32 x 8
#pragma unroll
    for (int i = 0; i < 4; i++)
        tile[ty + i * 8][tx] = w[(size_t)(bk + ty + i * 8) * DIM + bn + tx];
    __syncthreads();
#pragma unroll
    for (int i = 0; i < 4; i++)
        wT[(size_t)(bn + ty + i * 8) * DIM + bk + tx] = (half_t)tile[tx][ty + i * 8];
}

// ---------------------------------------------------------------------------
// MFMA GEMM: support[M,256] (f16) = x[M,256] (fp32, cast in staging) @ wT^T.
// Block tile 128x128, 4 waves (each 64x64 = 4x4 MFMA 16x16x32 tiles), BK=32.
// ---------------------------------------------------------------------------
#define BM 128
#define BN 128
#define BK 32
#define LDK 40

__global__ __launch_bounds__(256) void gemm_f16_kernel(const float* __restrict__ A,
                                                       const half_t* __restrict__ BT,
                                                       half_t* __restrict__ C, int M) {
    __shared__ half_t As[BM][LDK];
    __shared__ half_t Bs[BN][LDK];

    const int tid = threadIdx.x;
    const int wid = tid >> 6, lane = tid & 63;
    const int wm = wid & 1, wn = wid >> 1;
    const int row0 = blockIdx.x * BM;
    const int col0 = blockIdx.y * BN;
    const int lr = lane & 15;
    const int quad = lane >> 4;

    floatx4 acc[4][4] = {};

    const int ar = tid >> 1;
    const int ac = (tid & 1) * 16;
    const bool avalid = (row0 + ar) < M;
    const float* aptr = A + (size_t)(row0 + ar) * DIM + ac;

    for (int k0 = 0; k0 < DIM; k0 += BK) {
        // ---- stage A (fp32 -> f16): 128x32 ----
        {
            const float4* src = (const float4*)(aptr + k0);
            half_t* dst = &As[ar][ac];
#pragma unroll
            for (int i = 0; i < 4; i++) {
                float4 v = avalid ? src[i] : make_float4(0.f, 0.f, 0.f, 0.f);
                half4 h;
                h.x = (half_t)v.x; h.y = (half_t)v.y;
                h.z = (half_t)v.z; h.w = (half_t)v.w;
                ((half4*)dst)[i] = h;
            }
        }
        // ---- stage B (f16 copy): 128 n-rows x 32 k ----
        {
#pragma unroll
            for (int i = 0; i < 2; i++) {
                int ch = tid + i * 256;           // 512 chunks of 16 B
                int r = ch >> 2, cb = (ch & 3) * 8;
                half8 v = *(const half8*)(BT + (size_t)(col0 + r) * DIM + k0 + cb);
                *(half8*)&Bs[r][cb] = v;
            }
        }
        __syncthreads();

        half8 a[4], b[4];
#pragma unroll
        for (int i = 0; i < 4; i++)
            a[i] = *(const half8*)&As[wm * 64 + i * 16 + lr][quad * 8];
#pragma unroll
        for (int j = 0; j < 4; j++)
            b[j] = *(const half8*)&Bs[wn * 64 + j * 16 + lr][quad * 8];
#pragma unroll
        for (int i = 0; i < 4; i++)
#pragma unroll
            for (int j = 0; j < 4; j++)
                acc[i][j] = __builtin_amdgcn_mfma_f32_16x16x32_f16(a[i], b[j], acc[i][j], 0, 0, 0);
        __syncthreads();
    }

#pragma unroll
    for (int i = 0; i < 4; i++) {
#pragma unroll
        for (int j = 0; j < 4; j++) {
            int gc = col0 + wn * 64 + j * 16 + lr;
            int grb = row0 + wm * 64 + i * 16 + quad * 4;
#pragma unroll
            for (int r = 0; r < 4; r++) {
                int gr = grb + r;
                if (gr < M) C[(size_t)gr * DIM + gc] = (half_t)acc[i][j][r];
            }
        }
    }
}

// ---------------------------------------------------------------------------
// CSR construction: histogram -> multi-block scan -> permute (packed int2)
// ---------------------------------------------------------------------------
__global__ __launch_bounds__(256) void hist_kernel(const int* __restrict__ erow,
                                                   int* __restrict__ counts) {
    int idx = blockIdx.x * blockDim.x + threadIdx.x;   // N_EDGES/4 threads
    if (idx < N_EDGES / 4) {
        int4 r4 = ((const int4*)erow)[idx];
        atomicAdd(&counts[r4.x], 1);
        atomicAdd(&counts[r4.y], 1);
        atomicAdd(&counts[r4.z], 1);
        atomicAdd(&counts[r4.w], 1);
    }
}

#define NBLK_SCAN 391   // ceil(N_NODES / 256)

// per-block sums of counts
__global__ __launch_bounds__(256) void block_sum_kernel(const int* __restrict__ counts,
                                                        int* __restrict__ bsums) {
    int i = blockIdx.x * 256 + threadIdx.x;
    int c = (i < N_NODES) ? counts[i] : 0;
    int w = c;
#pragma unroll
    for (int off = 32; off > 0; off >>= 1) w += __shfl_down(w, off, 64);
    __shared__ int wsum[4];
    if ((threadIdx.x & 63) == 0) wsum[threadIdx.x >> 6] = w;
    __syncthreads();
    if (threadIdx.x == 0) bsums[blockIdx.x] = wsum[0] + wsum[1] + wsum[2] + wsum[3];
}

// exclusive scan of the 391 block sums (one block)
__global__ __launch_bounds__(512) void scan_sums_kernel(const int* __restrict__ bsums,
                                                        int* __restrict__ bpre) {
    __shared__ int s[512];
    int t = threadIdx.x;
    int v = (t < NBLK_SCAN) ? bsums[t] : 0;
    s[t] = v;
    __syncthreads();
    for (int off = 1; off < 512; off <<= 1) {
        int u = (t >= off) ? s[t - off] : 0;
        __syncthreads();
        s[t] += u;
        __syncthreads();
    }
    if (t < NBLK_SCAN) bpre[t] = s[t] - v;   // exclusive prefix
}

// block-local exclusive scan + add block prefix -> offsets, cursor init
__global__ __launch_bounds__(256) void scan_final_kernel(int* __restrict__ counts,
                                                         const int* __restrict__ bpre,
                                                         int* __restrict__ offsets) {
    __shared__ int s[256];
    int t = threadIdx.x;
    int i = blockIdx.x * 256 + t;
    int c = (i < N_NODES) ? counts[i] : 0;
    s[t] = c;
    __syncthreads();
    for (int off = 1; off < 256; off <<= 1) {
        int u = (t >= off) ? s[t - off] : 0;
        __syncthreads();
        s[t] += u;
        __syncthreads();
    }
    int ex = bpre[blockIdx.x] + s[t] - c;
    if (i < N_NODES) {
        offsets[i] = ex;
        counts[i] = ex;   // cursor for permute
    }
    if (i == 0) offsets[N_NODES] = N_EDGES;
}

__global__ __launch_bounds__(256) void permute_kernel(const int* __restrict__ erow,
                                                      const int* __restrict__ ecol,
                                                      const float* __restrict__ eval,
                                                      int* __restrict__ cursor,
                                                      int2* __restrict__ sedge) {
    int idx = blockIdx.x * blockDim.x + threadIdx.x;   // N_EDGES/4 threads
    if (idx < N_EDGES / 4) {
        int4 r4 = ((const int4*)erow)[idx];
        int4 c4 = ((const int4*)ecol)[idx];
        float4 v4 = ((const float4*)eval)[idx];
        int p;
        p = atomicAdd(&cursor[r4.x], 1); sedge[p] = make_int2(c4.x, __float_as_int(v4.x));
        p = atomicAdd(&cursor[r4.y], 1); sedge[p] = make_int2(c4.y, __float_as_int(v4.y));
        p = atomicAdd(&cursor[r4.z], 1); sedge[p] = make_int2(c4.z, __float_as_int(v4.z));
        p = atomicAdd(&cursor[r4.w], 1); sedge[p] = make_int2(c4.w, __float_as_int(v4.w));
    }
}

// ---------------------------------------------------------------------------
// CSR SpMM: one wave per row; half-wave per edge (32 lanes x 16 B = full row),
// 4 independent gathers in flight; cross-half shfl reduce; no atomics.
// ---------------------------------------------------------------------------
__global__ __launch_bounds__(256) void spmm_kernel(const half_t* __restrict__ support,
                                                   const int* __restrict__ offsets,
                                                   const int2* __restrict__ edges,
                                                   float* __restrict__ out) {
    int row = (blockIdx.x * blockDim.x + threadIdx.x) >> 6;
    if (row >= N_NODES) return;
    int lane = threadIdx.x & 63;
    int h = lane >> 5;   // which edge of a pair
    int j = lane & 31;   // 16 B chunk within the 512 B support row

    int beg = offsets[row];
    int end = offsets[row + 1];

    float acc[8] = {0.f, 0.f, 0.f, 0.f, 0.f, 0.f, 0.f, 0.f};
    int e = beg;
    for (; e + 7 < end; e += 8) {
        int2 q0 = edges[e + h];
        int2 q1 = edges[e + 2 + h];
        int2 q2 = edges[e + 4 + h];
        int2 q3 = edges[e + 6 + h];
        half8 s0 = *(const half8*)(support + (size_t)q0.x * DIM + j * 8);
        half8 s1 = *(const half8*)(support + (size_t)q1.x * DIM + j * 8);
        half8 s2 = *(const half8*)(support + (size_t)q2.x * DIM + j * 8);
        half8 s3 = *(const half8*)(support + (size_t)q3.x * DIM + j * 8);
        float v0 = __int_as_float(q0.y), v1 = __int_as_float(q1.y);
        float v2 = __int_as_float(q2.y), v3 = __int_as_float(q3.y);
#pragma unroll
        for (int d = 0; d < 8; d++)
            acc[d] += v0 * (float)s0[d] + v1 * (float)s1[d]
                    + v2 * (float)s2[d] + v3 * (float)s3[d];
    }
    for (; e + 1 < end; e += 2) {
        int2 q0 = edges[e + h];
        half8 s0 = *(const half8*)(support + (size_t)q0.x * DIM + j * 8);
        float v0 = __int_as_float(q0.y);
#pragma unroll
        for (int d = 0; d < 8; d++) acc[d] += v0 * (float)s0[d];
    }
    if (e < end) {   // odd tail: both halves load edge e; half 1 contributes 0
        int2 q0 = edges[e];
        half8 s0 = *(const half8*)(support + (size_t)q0.x * DIM + j * 8);
        float v0 = (h == 0) ? __int_as_float(q0.y) : 0.f;
#pragma unroll
        for (int d = 0; d < 8; d++) acc[d] += v0 * (float)s0[d];
    }

    // cross-half combine: lane (h, j) keeps dims j*8 + h*4 .. +4
    float r0, r1, r2, r3, g0, g1, g2, g3;
    if (h == 0) {
        r0 = acc[0]; r1 = acc[1]; r2 = acc[2]; r3 = acc[3];
        g0 = acc[4]; g1 = acc[5]; g2 = acc[6]; g3 = acc[7];
    } else {
        r0 = acc[4]; r1 = acc[5]; r2 = acc[6]; r3 = acc[7];
        g0 = acc[0]; g1 = acc[1]; g2 = acc[2]; g3 = acc[3];
    }
    r0 += __shfl_xor(g0, 32, 64);
    r1 += __shfl_xor(g1, 32, 64);
    r2 += __shfl_xor(g2, 32, 64);
    r3 += __shfl_xor(g3, 32, 64);

    *(float4*)(out + (size_t)row * DIM + j * 8 + h * 4) = make_float4(r0, r1, r2, r3);
}

extern "C" void kernel_launch(void* const* d_in, const int* in_sizes, int n_in,
                              void* d_out, int out_size, void* d_ws, size_t ws_size,
                              hipStream_t stream) {
    const float* x    = (const float*)d_in[0];
    const float* w    = (const float*)d_in[1];
    const int*   erow = (const int*)d_in[2];
    const int*   ecol = (const int*)d_in[3];
    const float* eval = (const float*)d_in[4];
    float* out = (float*)d_out;

    // workspace layout (77,731,200 B total — same footprint as before)
    char* ws = (char*)d_ws;
    half_t* support = (half_t*)ws;                       // 51,200,000 B
    int*    counts  = (int*)(ws + 51200000);             //    400,000 B (cursor)
    int*    offsets = (int*)(ws + 51600000);             //    400,004 B
    int2*   sedge   = (int2*)(ws + 52000128);            // 25,600,000 B (packed col,val)
    half_t* wT      = (half_t*)(ws + 77600128);          //    131,072 B
    // scan scratch lives in the sedge region (consumed before permute writes it)
    int*    bsums   = (int*)(ws + 52000128);             // 391 ints
    int*    bpre    = (int*)(ws + 52000128 + 2048);      // 391 ints

    hipMemsetAsync(counts, 0, N_NODES * sizeof(int), stream);

    castw_kernel<<<dim3(8, 8), 256, 0, stream>>>(w, wT);

    dim3 ggrid((N_NODES + BM - 1) / BM, DIM / BN);
    gemm_f16_kernel<<<ggrid, 256, 0, stream>>>(x, wT, support, N_NODES);

    hist_kernel<<<(N_EDGES / 4 + 255) / 256, 256, 0, stream>>>(erow, counts);
    block_sum_kernel<<<NBLK_SCAN, 256, 0, stream>>>(counts, bsums);
    scan_sums_kernel<<<1, 512, 0, stream>>>(bsums, bpre);
    scan_final_kernel<<<NBLK_SCAN, 256, 0, stream>>>(counts, bpre, offsets);
    permute_kernel<<<(N_EDGES / 4 + 255) / 256, 256, 0, stream>>>(erow, ecol, eval,
                                                                  counts, sedge);

    spmm_kernel<<<(N_NODES * 64 + 255) / 256, 256, 0, stream>>>(support, offsets,
                                                                sedge, out);
}

// Round 2
// 566.043 us; speedup vs baseline: 1.7568x; 1.3829x over previous
//
#include <hip/hip_runtime.h>

#define N_NODES 100000
#define N_EDGES 3200000
#define DIM 256

typedef _Float16 half_t;
typedef __attribute__((ext_vector_type(4))) _Float16 half4;
typedef __attribute__((ext_vector_type(8))) _Float16 half8;
typedef __attribute__((ext_vector_type(4))) float floatx4;

// ---------------------------------------------------------------------------
// W cast+transpose: wT[n][k] = (f16) w[k][n].  256x256, grid(8,8) x 256 thr.
// ---------------------------------------------------------------------------
__global__ __launch_bounds__(256) void castw_kernel(const float* __restrict__ w,
                                                    half_t* __restrict__ wT) {
    __shared__ float tile[32][33];
    int bk = blockIdx.x * 32;  // k block
    int bn = blockIdx.y * 32;  // n block
    int tx = threadIdx.x & 31, ty = threadIdx.x >> 5;  // 32 x 8
#pragma unroll
    for (int i = 0; i < 4; i++)
        tile[ty + i * 8][tx] = w[(size_t)(bk + ty + i * 8) * DIM + bn + tx];
    __syncthreads();
#pragma unroll
    for (int i = 0; i < 4; i++)
        wT[(size_t)(bn + ty + i * 8) * DIM + bk + tx] = (half_t)tile[tx][ty + i * 8];
}

// ---------------------------------------------------------------------------
// MFMA GEMM: support[M,256] (f16) = x[M,256] (fp32, cast in staging) @ wT^T.
// Block tile 128x128, 4 waves (each 64x64 = 4x4 MFMA 16x16x32 tiles), BK=32.
// ---------------------------------------------------------------------------
#define BM 128
#define BN 128
#define BK 32
#define LDK 40

__global__ __launch_bounds__(256) void gemm_f16_kernel(const float* __restrict__ A,
                                                       const half_t* __restrict__ BT,
                                                       half_t* __restrict__ C, int M) {
    __shared__ half_t As[BM][LDK];
    __shared__ half_t Bs[BN][LDK];

    const int tid = threadIdx.x;
    const int wid = tid >> 6, lane = tid & 63;
    const int wm = wid & 1, wn = wid >> 1;
    const int row0 = blockIdx.x * BM;
    const int col0 = blockIdx.y * BN;
    const int lr = lane & 15;
    const int quad = lane >> 4;

    floatx4 acc[4][4] = {};

    const int ar = tid >> 1;
    const int ac = (tid & 1) * 16;
    const bool avalid = (row0 + ar) < M;
    const float* aptr = A + (size_t)(row0 + ar) * DIM + ac;

    for (int k0 = 0; k0 < DIM; k0 += BK) {
        // ---- stage A (fp32 -> f16): 128x32 ----
        {
            const float4* src = (const float4*)(aptr + k0);
            half_t* dst = &As[ar][ac];
#pragma unroll
            for (int i = 0; i < 4; i++) {
                float4 v = avalid ? src[i] : make_float4(0.f, 0.f, 0.f, 0.f);
                half4 h;
                h.x = (half_t)v.x; h.y = (half_t)v.y;
                h.z = (half_t)v.z; h.w = (half_t)v.w;
                ((half4*)dst)[i] = h;
            }
        }
        // ---- stage B (f16 copy): 128 n-rows x 32 k ----
        {
#pragma unroll
            for (int i = 0; i < 2; i++) {
                int ch = tid + i * 256;           // 512 chunks of 16 B
                int r = ch >> 2, cb = (ch & 3) * 8;
                half8 v = *(const half8*)(BT + (size_t)(col0 + r) * DIM + k0 + cb);
                *(half8*)&Bs[r][cb] = v;
            }
        }
        __syncthreads();

        half8 a[4], b[4];
#pragma unroll
        for (int i = 0; i < 4; i++)
            a[i] = *(const half8*)&As[wm * 64 + i * 16 + lr][quad * 8];
#pragma unroll
        for (int j = 0; j < 4; j++)
            b[j] = *(const half8*)&Bs[wn * 64 + j * 16 + lr][quad * 8];
#pragma unroll
        for (int i = 0; i < 4; i++)
#pragma unroll
            for (int j = 0; j < 4; j++)
                acc[i][j] = __builtin_amdgcn_mfma_f32_16x16x32_f16(a[i], b[j], acc[i][j], 0, 0, 0);
        __syncthreads();
    }

#pragma unroll
    for (int i = 0; i < 4; i++) {
#pragma unroll
        for (int j = 0; j < 4; j++) {
            int gc = col0 + wn * 64 + j * 16 + lr;
            int grb = row0 + wm * 64 + i * 16 + quad * 4;
#pragma unroll
            for (int r = 0; r < 4; r++) {
                int gr = grb + r;
                if (gr < M) C[(size_t)gr * DIM + gc] = (half_t)acc[i][j][r];
            }
        }
    }
}

// ---------------------------------------------------------------------------
// CSR construction via 2-level counting sort.
// Bucket = row >> 8 (391 buckets of <=256 rows). All per-edge atomics in LDS.
// ---------------------------------------------------------------------------
#define NBUCK 391
#define EPB 4096                       // edges per block in bucket kernels
#define NEB ((N_EDGES + EPB - 1) / EPB)  // 782 blocks

// Pass 1a: exact bucket histogram (LDS-aggregated)
__global__ __launch_bounds__(256) void bucket_hist_kernel(const int* __restrict__ erow,
                                                          int* __restrict__ bcnt) {
    __shared__ int lh[NBUCK];
    for (int b = threadIdx.x; b < NBUCK; b += 256) lh[b] = 0;
    __syncthreads();
    int base4 = blockIdx.x * (EPB / 4);
#pragma unroll
    for (int i = 0; i < 4; i++) {
        int idx4 = base4 + i * 256 + threadIdx.x;
        if (idx4 < N_EDGES / 4) {
            int4 r4 = ((const int4*)erow)[idx4];
            atomicAdd(&lh[r4.x >> 8], 1);
            atomicAdd(&lh[r4.y >> 8], 1);
            atomicAdd(&lh[r4.z >> 8], 1);
            atomicAdd(&lh[r4.w >> 8], 1);
        }
    }
    __syncthreads();
    for (int b = threadIdx.x; b < NBUCK; b += 256)
        if (lh[b]) atomicAdd(&bcnt[b * 16], lh[b]);   // stride-16: 1 counter/line
}

// Pass 1b: scan 391 bucket counts -> bases; re-init bcnt as chunk cursor
__global__ __launch_bounds__(512) void scan_buckets_kernel(int* __restrict__ bcnt,
                                                           int* __restrict__ bbase,
                                                           int* __restrict__ offsets) {
    __shared__ int s[512];
    int t = threadIdx.x;
    int v = (t < NBUCK) ? bcnt[t * 16] : 0;
    s[t] = v;
    __syncthreads();
    for (int off = 1; off < 512; off <<= 1) {
        int u = (t >= off) ? s[t - off] : 0;
        __syncthreads();
        s[t] += u;
        __syncthreads();
    }
    if (t < NBUCK) {
        int ex = s[t] - v;
        bbase[t] = ex;
        bcnt[t * 16] = ex;   // cursor for bucket_scatter
    }
    if (t == 0) { bbase[NBUCK] = N_EDGES; offsets[N_NODES] = N_EDGES; }
}

// Pass 1c: scatter edges into bucket-major tmp (chunk reservation per block)
// tmp record: .x = ((row & 255) << 17) | col   (col < 2^17), .y = val bits
__global__ __launch_bounds__(256) void bucket_scatter_kernel(const int* __restrict__ erow,
                                                             const int* __restrict__ ecol,
                                                             const float* __restrict__ eval,
                                                             int* __restrict__ bcursor,
                                                             int2* __restrict__ tmp) {
    __shared__ int lh[NBUCK];
    __shared__ int lbase[NBUCK];
    for (int b = threadIdx.x; b < NBUCK; b += 256) lh[b] = 0;
    __syncthreads();

    int base4 = blockIdx.x * (EPB / 4);
    int4 r4[4], c4[4];
    float4 v4[4];
    bool ok[4];
#pragma unroll
    for (int i = 0; i < 4; i++) {
        int idx4 = base4 + i * 256 + threadIdx.x;
        ok[i] = idx4 < N_EDGES / 4;
        if (ok[i]) {
            r4[i] = ((const int4*)erow)[idx4];
            c4[i] = ((const int4*)ecol)[idx4];
            v4[i] = ((const float4*)eval)[idx4];
            atomicAdd(&lh[r4[i].x >> 8], 1);
            atomicAdd(&lh[r4[i].y >> 8], 1);
            atomicAdd(&lh[r4[i].z >> 8], 1);
            atomicAdd(&lh[r4[i].w >> 8], 1);
        }
    }
    __syncthreads();
    for (int b = threadIdx.x; b < NBUCK; b += 256) {
        int c = lh[b];
        lbase[b] = c ? atomicAdd(&bcursor[b * 16], c) : 0;
        lh[b] = 0;   // becomes local rank cursor
    }
    __syncthreads();

#define SCAT(R, C, V)                                                     \
    {                                                                     \
        int _r = (R), _c = (C);                                           \
        int _b = _r >> 8;                                                 \
        int _rank = atomicAdd(&lh[_b], 1);                                \
        tmp[lbase[_b] + _rank] =                                          \
            make_int2(((_r & 255) << 17) | _c, __float_as_int(V));        \
    }
#pragma unroll
    for (int i = 0; i < 4; i++) {
        if (!ok[i]) continue;
        SCAT(r4[i].x, c4[i].x, v4[i].x);
        SCAT(r4[i].y, c4[i].y, v4[i].y);
        SCAT(r4[i].z, c4[i].z, v4[i].z);
        SCAT(r4[i].w, c4[i].w, v4[i].w);
    }
#undef SCAT
}

// Pass 2: one block per bucket. LDS hist + scan of 256 local rows ->
// offsets + in-bucket CSR scatter (64 KB destination window, no global atomics)
__global__ __launch_bounds__(256) void bucket_to_csr_kernel(const int2* __restrict__ tmp,
                                                            const int* __restrict__ bbase,
                                                            int* __restrict__ offsets,
                                                            int2* __restrict__ sedge) {
    __shared__ int lh[256];
    __shared__ int s[256];
    const int b = blockIdx.x;
    const int t = threadIdx.x;
    const int beg = bbase[b], end = bbase[b + 1];

    lh[t] = 0;
    __syncthreads();
    for (int e = beg + t; e < end; e += 256)
        atomicAdd(&lh[tmp[e].x >> 17], 1);
    __syncthreads();

    int c = lh[t];
    s[t] = c;
    __syncthreads();
    for (int off = 1; off < 256; off <<= 1) {
        int u = (t >= off) ? s[t - off] : 0;
        __syncthreads();
        s[t] += u;
        __syncthreads();
    }
    int ex = s[t] - c;
    int row = (b << 8) + t;
    if (row < N_NODES) offsets[row] = beg + ex;
    lh[t] = ex;   // local cursor
    __syncthreads();

    for (int e = beg + t; e < end; e += 256) {
        int2 q = tmp[e];
        int lr = q.x >> 17;
        int rank = atomicAdd(&lh[lr], 1);
        sedge[beg + rank] = make_int2(q.x & 0x1FFFF, q.y);
    }
}

// ---------------------------------------------------------------------------
// CSR SpMM: one wave per row; half-wave per edge (32 lanes x 16 B = full row),
// 4 independent gathers in flight; cross-half shfl reduce; no atomics.
// ---------------------------------------------------------------------------
__global__ __launch_bounds__(256) void spmm_kernel(const half_t* __restrict__ support,
                                                   const int* __restrict__ offsets,
                                                   const int2* __restrict__ edges,
                                                   float* __restrict__ out) {
    int row = (blockIdx.x * blockDim.x + threadIdx.x) >> 6;
    if (row >= N_NODES) return;
    int lane = threadIdx.x & 63;
    int h = lane >> 5;   // which edge of a pair
    int j = lane & 31;   // 16 B chunk within the 512 B support row

    int beg = offsets[row];
    int end = offsets[row + 1];

    float acc[8] = {0.f, 0.f, 0.f, 0.f, 0.f, 0.f, 0.f, 0.f};
    int e = beg;
    for (; e + 7 < end; e += 8) {
        int2 q0 = edges[e + h];
        int2 q1 = edges[e + 2 + h];
        int2 q2 = edges[e + 4 + h];
        int2 q3 = edges[e + 6 + h];
        half8 s0 = *(const half8*)(support + (size_t)q0.x * DIM + j * 8);
        half8 s1 = *(const half8*)(support + (size_t)q1.x * DIM + j * 8);
        half8 s2 = *(const half8*)(support + (size_t)q2.x * DIM + j * 8);
        half8 s3 = *(const half8*)(support + (size_t)q3.x * DIM + j * 8);
        float v0 = __int_as_float(q0.y), v1 = __int_as_float(q1.y);
        float v2 = __int_as_float(q2.y), v3 = __int_as_float(q3.y);
#pragma unroll
        for (int d = 0; d < 8; d++)
            acc[d] += v0 * (float)s0[d] + v1 * (float)s1[d]
                    + v2 * (float)s2[d] + v3 * (float)s3[d];
    }
    for (; e + 1 < end; e += 2) {
        int2 q0 = edges[e + h];
        half8 s0 = *(const half8*)(support + (size_t)q0.x * DIM + j * 8);
        float v0 = __int_as_float(q0.y);
#pragma unroll
        for (int d = 0; d < 8; d++) acc[d] += v0 * (float)s0[d];
    }
    if (e < end) {   // odd tail: both halves load edge e; half 1 contributes 0
        int2 q0 = edges[e];
        half8 s0 = *(const half8*)(support + (size_t)q0.x * DIM + j * 8);
        float v0 = (h == 0) ? __int_as_float(q0.y) : 0.f;
#pragma unroll
        for (int d = 0; d < 8; d++) acc[d] += v0 * (float)s0[d];
    }

    // cross-half combine: lane (h, j) keeps dims j*8 + h*4 .. +4
    float r0, r1, r2, r3, g0, g1, g2, g3;
    if (h == 0) {
        r0 = acc[0]; r1 = acc[1]; r2 = acc[2]; r3 = acc[3];
        g0 = acc[4]; g1 = acc[5]; g2 = acc[6]; g3 = acc[7];
    } else {
        r0 = acc[4]; r1 = acc[5]; r2 = acc[6]; r3 = acc[7];
        g0 = acc[0]; g1 = acc[1]; g2 = acc[2]; g3 = acc[3];
    }
    r0 += __shfl_xor(g0, 32, 64);
    r1 += __shfl_xor(g1, 32, 64);
    r2 += __shfl_xor(g2, 32, 64);
    r3 += __shfl_xor(g3, 32, 64);

    *(float4*)(out + (size_t)row * DIM + j * 8 + h * 4) = make_float4(r0, r1, r2, r3);
}

extern "C" void kernel_launch(void* const* d_in, const int* in_sizes, int n_in,
                              void* d_out, int out_size, void* d_ws, size_t ws_size,
                              hipStream_t stream) {
    const float* x    = (const float*)d_in[0];
    const float* w    = (const float*)d_in[1];
    const int*   erow = (const int*)d_in[2];
    const int*   ecol = (const int*)d_in[3];
    const float* eval = (const float*)d_in[4];
    float* out = (float*)d_out;

    // workspace layout (77,357,792 B used; within previous 77.7 MB footprint)
    char* ws = (char*)d_ws;
    half_t* support = (half_t*)ws;                       // 51,200,000 B
    int*    offsets = (int*)(ws + 51200000);             //    400,004 B
    int2*   sedge   = (int2*)(ws + 51600128);            // 25,600,000 B (col,val)
    half_t* wT      = (half_t*)(ws + 77200128);          //    131,072 B
    int*    bcnt    = (int*)(ws + 77331200);             // 391*64 B (stride-16 counters)
    int*    bbase   = (int*)(ws + 77356224);             // 392*4 B
    // bucket-major tmp edges live in d_out (dead until spmm fully overwrites it)
    int2*   tmp     = (int2*)d_out;                      // 25,600,000 B scratch

    hipMemsetAsync(bcnt, 0, NBUCK * 16 * sizeof(int), stream);

    castw_kernel<<<dim3(8, 8), 256, 0, stream>>>(w, wT);

    dim3 ggrid((N_NODES + BM - 1) / BM, DIM / BN);
    gemm_f16_kernel<<<ggrid, 256, 0, stream>>>(x, wT, support, N_NODES);

    bucket_hist_kernel<<<NEB, 256, 0, stream>>>(erow, bcnt);
    scan_buckets_kernel<<<1, 512, 0, stream>>>(bcnt, bbase, offsets);
    bucket_scatter_kernel<<<NEB, 256, 0, stream>>>(erow, ecol, eval, bcnt, tmp);
    bucket_to_csr_kernel<<<NBUCK, 256, 0, stream>>>(tmp, bbase, offsets, sedge);

    spmm_kernel<<<(N_NODES * 64 + 255) / 256, 256, 0, stream>>>(support, offsets,
                                                                sedge, out);
}

// Round 3
// 544.392 us; speedup vs baseline: 1.8267x; 1.0398x over previous
//
#include <hip/hip_runtime.h>

#define N_NODES 100000
#define N_EDGES 3200000
#define DIM 256

typedef _Float16 half_t;
typedef __attribute__((ext_vector_type(4))) _Float16 half4;
typedef __attribute__((ext_vector_type(8))) _Float16 half8;
typedef __attribute__((ext_vector_type(4))) float floatx4;

// ---------------------------------------------------------------------------
// W cast+transpose: wT[n][k] = (f16) w[k][n].  256x256, grid(8,8) x 256 thr.
// ---------------------------------------------------------------------------
__global__ __launch_bounds__(256) void castw_kernel(const float* __restrict__ w,
                                                    half_t* __restrict__ wT) {
    __shared__ float tile[32][33];
    int bk = blockIdx.x * 32;  // k block
    int bn = blockIdx.y * 32;  // n block
    int tx = threadIdx.x & 31, ty = threadIdx.x >> 5;  // 32 x 8
#pragma unroll
    for (int i = 0; i < 4; i++)
        tile[ty + i * 8][tx] = w[(size_t)(bk + ty + i * 8) * DIM + bn + tx];
    __syncthreads();
#pragma unroll
    for (int i = 0; i < 4; i++)
        wT[(size_t)(bn + ty + i * 8) * DIM + bk + tx] = (half_t)tile[tx][ty + i * 8];
}

// ---------------------------------------------------------------------------
// MFMA GEMM: support[M,256] (f16) = x[M,256] (fp32) @ wT^T.
// Block tile 128x256 (full N in one pass -> A read once), 512 thr / 8 waves,
// wave grid 2(m) x 4(n), each wave 64x64 = 4x4 MFMA 16x16x32 tiles, BK=32.
// ---------------------------------------------------------------------------
#define BM 128
#define BK 32
#define LDK 40

__global__ __launch_bounds__(512) void gemm_f16_kernel(const float* __restrict__ A,
                                                       const half_t* __restrict__ BT,
                                                       half_t* __restrict__ C, int M) {
    __shared__ half_t As[BM][LDK];
    __shared__ half_t Bs[256][LDK];

    const int tid = threadIdx.x;
    const int wid = tid >> 6, lane = tid & 63;
    const int wm = wid & 1, wn = wid >> 1;   // 2 x 4
    const int row0 = blockIdx.x * BM;
    const int lr = lane & 15;
    const int quad = lane >> 4;

    floatx4 acc[4][4] = {};

    // A staging map: 128 rows x 32 k fp32 = 1024 float4; thread -> 2 float4
    const int ar = tid >> 2;
    const int ac = (tid & 3) * 8;
    const bool avalid = (row0 + ar) < M;
    const float* aptr = A + (size_t)(row0 + ar) * DIM + ac;

    for (int k0 = 0; k0 < DIM; k0 += BK) {
        // ---- stage A (fp32 -> f16): 128x32 ----
        {
            const float4* src = (const float4*)(aptr + k0);
            half_t* dst = &As[ar][ac];
#pragma unroll
            for (int i = 0; i < 2; i++) {
                float4 v = avalid ? src[i] : make_float4(0.f, 0.f, 0.f, 0.f);
                half4 h;
                h.x = (half_t)v.x; h.y = (half_t)v.y;
                h.z = (half_t)v.z; h.w = (half_t)v.w;
                ((half4*)dst)[i] = h;
            }
        }
        // ---- stage B (f16 copy): 256 n-rows x 32 k = 1024 16B chunks ----
        {
#pragma unroll
            for (int i = 0; i < 2; i++) {
                int ch = tid + i * 512;
                int r = ch >> 2, cb = (ch & 3) * 8;
                half8 v = *(const half8*)(BT + (size_t)r * DIM + k0 + cb);
                *(half8*)&Bs[r][cb] = v;
            }
        }
        __syncthreads();

        half8 a[4], b[4];
#pragma unroll
        for (int i = 0; i < 4; i++)
            a[i] = *(const half8*)&As[wm * 64 + i * 16 + lr][quad * 8];
#pragma unroll
        for (int j = 0; j < 4; j++)
            b[j] = *(const half8*)&Bs[wn * 64 + j * 16 + lr][quad * 8];
#pragma unroll
        for (int i = 0; i < 4; i++)
#pragma unroll
            for (int j = 0; j < 4; j++)
                acc[i][j] = __builtin_amdgcn_mfma_f32_16x16x32_f16(a[i], b[j], acc[i][j], 0, 0, 0);
        __syncthreads();
    }

#pragma unroll
    for (int i = 0; i < 4; i++) {
#pragma unroll
        for (int j = 0; j < 4; j++) {
            int gc = wn * 64 + j * 16 + lr;
            int grb = row0 + wm * 64 + i * 16 + quad * 4;
#pragma unroll
            for (int r = 0; r < 4; r++) {
                int gr = grb + r;
                if (gr < M) C[(size_t)gr * DIM + gc] = (half_t)acc[i][j][r];
            }
        }
    }
}

// ---------------------------------------------------------------------------
// CSR construction via 2-level counting sort.
// Bucket = row >> 8 (391 buckets of <=256 rows). All per-edge atomics in LDS.
// ---------------------------------------------------------------------------
#define NBUCK 391
#define EPB 16384                        // edges per block in bucket kernels
#define NEB ((N_EDGES + EPB - 1) / EPB)  // 196 blocks

// Pass 1a: exact bucket histogram (LDS-aggregated)
__global__ __launch_bounds__(256) void bucket_hist_kernel(const int* __restrict__ erow,
                                                          int* __restrict__ bcnt) {
    __shared__ int lh[NBUCK];
    for (int b = threadIdx.x; b < NBUCK; b += 256) lh[b] = 0;
    __syncthreads();
    int base4 = blockIdx.x * (EPB / 4);
#pragma unroll
    for (int i = 0; i < 16; i++) {
        int idx4 = base4 + i * 256 + threadIdx.x;
        if (idx4 < N_EDGES / 4) {
            int4 r4 = ((const int4*)erow)[idx4];
            atomicAdd(&lh[r4.x >> 8], 1);
            atomicAdd(&lh[r4.y >> 8], 1);
            atomicAdd(&lh[r4.z >> 8], 1);
            atomicAdd(&lh[r4.w >> 8], 1);
        }
    }
    __syncthreads();
    for (int b = threadIdx.x; b < NBUCK; b += 256)
        if (lh[b]) atomicAdd(&bcnt[b * 16], lh[b]);   // stride-16: 1 counter/line
}

// Pass 1b: scan 391 bucket counts -> bases; re-init bcnt as chunk cursor
__global__ __launch_bounds__(512) void scan_buckets_kernel(int* __restrict__ bcnt,
                                                           int* __restrict__ bbase,
                                                           int* __restrict__ offsets) {
    __shared__ int s[512];
    int t = threadIdx.x;
    int v = (t < NBUCK) ? bcnt[t * 16] : 0;
    s[t] = v;
    __syncthreads();
    for (int off = 1; off < 512; off <<= 1) {
        int u = (t >= off) ? s[t - off] : 0;
        __syncthreads();
        s[t] += u;
        __syncthreads();
    }
    if (t < NBUCK) {
        int ex = s[t] - v;
        bbase[t] = ex;
        bcnt[t * 16] = ex;   // cursor for bucket_scatter
    }
    if (t == 0) { bbase[NBUCK] = N_EDGES; offsets[N_NODES] = N_EDGES; }
}

// Pass 1c: scatter edges into bucket-major tmp (chunk reservation per block).
// EPB=16384 -> ~42 edges (336 B) per bucket-run: near-full-line writebacks.
// Phase 2 re-reads inputs (L2-hot) instead of register-caching them.
// tmp record: .x = ((row & 255) << 17) | col   (col < 2^17), .y = val bits
__global__ __launch_bounds__(256) void bucket_scatter_kernel(const int* __restrict__ erow,
                                                             const int* __restrict__ ecol,
                                                             const float* __restrict__ eval,
                                                             int* __restrict__ bcursor,
                                                             int2* __restrict__ tmp) {
    __shared__ int lh[NBUCK];
    __shared__ int lbase[NBUCK];
    for (int b = threadIdx.x; b < NBUCK; b += 256) lh[b] = 0;
    __syncthreads();

    int base4 = blockIdx.x * (EPB / 4);
    // phase 1: local histogram
#pragma unroll
    for (int i = 0; i < 16; i++) {
        int idx4 = base4 + i * 256 + threadIdx.x;
        if (idx4 < N_EDGES / 4) {
            int4 r4 = ((const int4*)erow)[idx4];
            atomicAdd(&lh[r4.x >> 8], 1);
            atomicAdd(&lh[r4.y >> 8], 1);
            atomicAdd(&lh[r4.z >> 8], 1);
            atomicAdd(&lh[r4.w >> 8], 1);
        }
    }
    __syncthreads();
    // reserve contiguous chunks
    for (int b = threadIdx.x; b < NBUCK; b += 256) {
        int c = lh[b];
        lbase[b] = c ? atomicAdd(&bcursor[b * 16], c) : 0;
        lh[b] = 0;   // becomes local rank cursor
    }
    __syncthreads();

    // phase 2: re-read & scatter
#define SCAT(R, C, V)                                                     \
    {                                                                     \
        int _r = (R), _c = (C);                                           \
        int _b = _r >> 8;                                                 \
        int _rank = atomicAdd(&lh[_b], 1);                                \
        tmp[lbase[_b] + _rank] =                                          \
            make_int2(((_r & 255) << 17) | _c, __float_as_int(V));        \
    }
#pragma unroll
    for (int i = 0; i < 16; i++) {
        int idx4 = base4 + i * 256 + threadIdx.x;
        if (idx4 < N_EDGES / 4) {
            int4 r4 = ((const int4*)erow)[idx4];
            int4 c4 = ((const int4*)ecol)[idx4];
            float4 v4 = ((const float4*)eval)[idx4];
            SCAT(r4.x, c4.x, v4.x);
            SCAT(r4.y, c4.y, v4.y);
            SCAT(r4.z, c4.z, v4.z);
            SCAT(r4.w, c4.w, v4.w);
        }
    }
#undef SCAT
}

// Pass 2: one block per bucket. LDS hist + scan of 256 local rows ->
// offsets + in-bucket CSR scatter (64 KB destination window, no global atomics)
__global__ __launch_bounds__(256) void bucket_to_csr_kernel(const int2* __restrict__ tmp,
                                                            const int* __restrict__ bbase,
                                                            int* __restrict__ offsets,
                                                            int2* __restrict__ sedge) {
    __shared__ int lh[256];
    __shared__ int s[256];
    const int b = blockIdx.x;
    const int t = threadIdx.x;
    const int beg = bbase[b], end = bbase[b + 1];

    lh[t] = 0;
    __syncthreads();
    for (int e = beg + t; e < end; e += 256)
        atomicAdd(&lh[tmp[e].x >> 17], 1);
    __syncthreads();

    int c = lh[t];
    s[t] = c;
    __syncthreads();
    for (int off = 1; off < 256; off <<= 1) {
        int u = (t >= off) ? s[t - off] : 0;
        __syncthreads();
        s[t] += u;
        __syncthreads();
    }
    int ex = s[t] - c;
    int row = (b << 8) + t;
    if (row < N_NODES) offsets[row] = beg + ex;
    lh[t] = ex;   // local cursor
    __syncthreads();

    for (int e = beg + t; e < end; e += 256) {
        int2 q = tmp[e];
        int lr = q.x >> 17;
        int rank = atomicAdd(&lh[lr], 1);
        sedge[beg + rank] = make_int2(q.x & 0x1FFFF, q.y);
    }
}

// ---------------------------------------------------------------------------
// CSR SpMM: one wave per row; half-wave per edge (32 lanes x 16 B = full row).
// int4 edge loads (2 edges/load) + 16-edge unroll = 8 gathers in flight/lane.
// Cross-half shfl reduce; no atomics.
// ---------------------------------------------------------------------------
__global__ __launch_bounds__(256) void spmm_kernel(const half_t* __restrict__ support,
                                                   const int* __restrict__ offsets,
                                                   const int2* __restrict__ edges,
                                                   float* __restrict__ out) {
    int row = (blockIdx.x * blockDim.x + threadIdx.x) >> 6;
    if (row >= N_NODES) return;
    int lane = threadIdx.x & 63;
    int h = lane >> 5;   // which half-wave
    int j = lane & 31;   // 16 B chunk within the 512 B support row

    int beg = offsets[row];
    int end = offsets[row + 1];

    float acc[8] = {0.f, 0.f, 0.f, 0.f, 0.f, 0.f, 0.f, 0.f};
    int e = beg;

    // alignment peel: make e even so int4 edge loads are 16B-aligned
    if ((e & 1) && e < end) {
        int2 q0 = edges[e];
        half8 s0 = *(const half8*)(support + (size_t)q0.x * DIM + j * 8);
        float v0 = (h == 0) ? __int_as_float(q0.y) : 0.f;
#pragma unroll
        for (int d = 0; d < 8; d++) acc[d] += v0 * (float)s0[d];
        e++;
    }

    // main: 16 edges/iter; half h takes pairs {e+2h, e+2h+1} of each quad
    for (; e + 15 < end; e += 16) {
        int4 pa = *(const int4*)(edges + e + 2 * h);
        int4 pb = *(const int4*)(edges + e + 4 + 2 * h);
        int4 pc = *(const int4*)(edges + e + 8 + 2 * h);
        int4 pd = *(const int4*)(edges + e + 12 + 2 * h);
        half8 s0 = *(const half8*)(support + (size_t)pa.x * DIM + j * 8);
        half8 s1 = *(const half8*)(support + (size_t)pa.z * DIM + j * 8);
        half8 s2 = *(const half8*)(support + (size_t)pb.x * DIM + j * 8);
        half8 s3 = *(const half8*)(support + (size_t)pb.z * DIM + j * 8);
        half8 s4 = *(const half8*)(support + (size_t)pc.x * DIM + j * 8);
        half8 s5 = *(const half8*)(support + (size_t)pc.z * DIM + j * 8);
        half8 s6 = *(const half8*)(support + (size_t)pd.x * DIM + j * 8);
        half8 s7 = *(const half8*)(support + (size_t)pd.z * DIM + j * 8);
        float v0 = __int_as_float(pa.y), v1 = __int_as_float(pa.w);
        float v2 = __int_as_float(pb.y), v3 = __int_as_float(pb.w);
        float v4 = __int_as_float(pc.y), v5 = __int_as_float(pc.w);
        float v6 = __int_as_float(pd.y), v7 = __int_as_float(pd.w);
#pragma unroll
        for (int d = 0; d < 8; d++)
            acc[d] += v0 * (float)s0[d] + v1 * (float)s1[d]
                    + v2 * (float)s2[d] + v3 * (float)s3[d]
                    + v4 * (float)s4[d] + v5 * (float)s5[d]
                    + v6 * (float)s6[d] + v7 * (float)s7[d];
    }
    // pair tail
    for (; e + 1 < end; e += 2) {
        int2 q0 = edges[e + h];
        half8 s0 = *(const half8*)(support + (size_t)q0.x * DIM + j * 8);
        float v0 = __int_as_float(q0.y);
#pragma unroll
        for (int d = 0; d < 8; d++) acc[d] += v0 * (float)s0[d];
    }
    // odd tail: both halves load edge e; half 1 contributes 0
    if (e < end) {
        int2 q0 = edges[e];
        half8 s0 = *(const half8*)(support + (size_t)q0.x * DIM + j * 8);
        float v0 = (h == 0) ? __int_as_float(q0.y) : 0.f;
#pragma unroll
        for (int d = 0; d < 8; d++) acc[d] += v0 * (float)s0[d];
    }

    // cross-half combine: lane (h, j) keeps dims j*8 + h*4 .. +4
    float r0, r1, r2, r3, g0, g1, g2, g3;
    if (h == 0) {
        r0 = acc[0]; r1 = acc[1]; r2 = acc[2]; r3 = acc[3];
        g0 = acc[4]; g1 = acc[5]; g2 = acc[6]; g3 = acc[7];
    } else {
        r0 = acc[4]; r1 = acc[5]; r2 = acc[6]; r3 = acc[7];
        g0 = acc[0]; g1 = acc[1]; g2 = acc[2]; g3 = acc[3];
    }
    r0 += __shfl_xor(g0, 32, 64);
    r1 += __shfl_xor(g1, 32, 64);
    r2 += __shfl_xor(g2, 32, 64);
    r3 += __shfl_xor(g3, 32, 64);

    *(float4*)(out + (size_t)row * DIM + j * 8 + h * 4) = make_float4(r0, r1, r2, r3);
}

extern "C" void kernel_launch(void* const* d_in, const int* in_sizes, int n_in,
                              void* d_out, int out_size, void* d_ws, size_t ws_size,
                              hipStream_t stream) {
    const float* x    = (const float*)d_in[0];
    const float* w    = (const float*)d_in[1];
    const int*   erow = (const int*)d_in[2];
    const int*   ecol = (const int*)d_in[3];
    const float* eval = (const float*)d_in[4];
    float* out = (float*)d_out;

    // workspace layout (77,357,792 B used)
    char* ws = (char*)d_ws;
    half_t* support = (half_t*)ws;                       // 51,200,000 B
    int*    offsets = (int*)(ws + 51200000);             //    400,004 B
    int2*   sedge   = (int2*)(ws + 51600128);            // 25,600,000 B (col,val)
    half_t* wT      = (half_t*)(ws + 77200128);          //    131,072 B
    int*    bcnt    = (int*)(ws + 77331200);             // 391*64 B (stride-16 counters)
    int*    bbase   = (int*)(ws + 77356224);             // 392*4 B
    // bucket-major tmp edges live in d_out (dead until spmm fully overwrites it)
    int2*   tmp     = (int2*)d_out;                      // 25,600,000 B scratch

    hipMemsetAsync(bcnt, 0, NBUCK * 16 * sizeof(int), stream);

    castw_kernel<<<dim3(8, 8), 256, 0, stream>>>(w, wT);

    dim3 ggrid((N_NODES + BM - 1) / BM, 1);
    gemm_f16_kernel<<<ggrid, 512, 0, stream>>>(x, wT, support, N_NODES);

    bucket_hist_kernel<<<NEB, 256, 0, stream>>>(erow, bcnt);
    scan_buckets_kernel<<<1, 512, 0, stream>>>(bcnt, bbase, offsets);
    bucket_scatter_kernel<<<NEB, 256, 0, stream>>>(erow, ecol, eval, bcnt, tmp);
    bucket_to_csr_kernel<<<NBUCK, 256, 0, stream>>>(tmp, bbase, offsets, sedge);

    spmm_kernel<<<(N_NODES * 64 + 255) / 256, 256, 0, stream>>>(support, offsets,
                                                                sedge, out);
}